// Round 4
// baseline (970.710 us; speedup 1.0000x reference)
//
#include <hip/hip_runtime.h>

// GRU_27212912787836 : 2-layer GRU, B=512, T=1024, IN=3, H=64 (fp32 in/out)
// bf16 MFMA internally, fp32 cell math/state.
//
// Round 4: r3 pipeline (32 blocks x 8 waves; waves 0-3 layer0 tile jt,
// waves 4-7 layer1 tile jt; h0 via W=8 LDS ring) with restructured sync:
//  - per-wave flag dwords + plain release stores (r3's shared ds_atomic_add
//    counter serialized 4 RMWs per sync round on one LDS address)
//  - ONE merged poll per step per stage (was two serial rounds): exchange
//    read moved to top-of-step; rings pre-zeroed so t=0 reads h(-1)=0.
//  - seq_out global stores after the flag release (off the serial chain).

typedef __attribute__((ext_vector_type(8))) short short8;   // 8 bf16
typedef __attribute__((ext_vector_type(4))) float floatx4;  // MFMA C/D

#define MFMA16(a, b, c) __builtin_amdgcn_mfma_f32_16x16x32_bf16((a), (b), (c), 0, 0, 0)

static constexpr int kB = 512;
static constexpr int kT = 1024;
static constexpr int kIN = 3;
static constexpr int kH = 64;
static constexpr int LDH = 72;  // padded LDS row stride (bf16): 2-way banks only
static constexpr int W   = 8;   // h0 ring depth (power of 2)

__device__ __forceinline__ unsigned short f2bf(float f) {
  unsigned u = __builtin_bit_cast(unsigned, f);
  return (unsigned short)((u + 0x7FFFu + ((u >> 16) & 1u)) >> 16);
}
__device__ __forceinline__ float sigm(float x) {
  return __builtin_amdgcn_rcpf(1.0f + __builtin_amdgcn_exp2f(-1.44269504f * x));
}
__device__ __forceinline__ float tanh_(float x) {
  return 1.0f - 2.0f * __builtin_amdgcn_rcpf(1.0f + __builtin_amdgcn_exp2f(2.88539008f * x));
}
__device__ __forceinline__ short8 cvt8(const float* p) {
  short8 f;
#pragma unroll
  for (int j = 0; j < 8; ++j) f[j] = (short)f2bf(p[j]);
  return f;
}
__device__ __forceinline__ unsigned umin4(unsigned a, unsigned b, unsigned c, unsigned d) {
  unsigned x = a < b ? a : b;
  unsigned y = c < d ? c : d;
  return x < y ? x : y;
}

__global__ __launch_bounds__(512, 2) void gru_kernel(
    const float* __restrict__ x,
    const float* __restrict__ Wih0, const float* __restrict__ Whh0,
    const float* __restrict__ bih0, const float* __restrict__ bhh0,
    const float* __restrict__ Wih1, const float* __restrict__ Whh1,
    const float* __restrict__ bih1, const float* __restrict__ bhh1,
    float* __restrict__ out) {
  const int tid  = threadIdx.x;
  const int lane = tid & 63;
  const int jt   = (tid >> 6) & 3;  // hidden tile 0..3
  const int lyr  = tid >> 8;        // 0: layer0 waves, 1: layer1 waves
  const int c    = lane & 15;
  const int grp  = lane >> 4;
  const int wb   = blockIdx.x * 16;

  __shared__ unsigned short ring0[W][16 * LDH];  // h0(t) stream, bf16
  __shared__ unsigned short ring1[2][16 * LDH];  // h1(t) exchange, bf16
  __shared__ unsigned flags[8];                  // per-wave step counters

  {  // zero rings (t=0 reads h(-1)=0 from them) + flags; one-time
    unsigned short* p0 = &ring0[0][0];
    for (int i = tid; i < W * 16 * LDH; i += 512) p0[i] = 0;
    unsigned short* p1 = &ring1[0][0];
    for (int i = tid; i < 2 * 16 * LDH; i += 512) p1[i] = 0;
    if (tid < 8) flags[tid] = 0;
  }
  __syncthreads();  // once, outside the loop

  volatile unsigned* vf = flags;
  // wait until min(l0 flags) >= t0 AND min(l1 flags) >= t1
  auto poll = [&](unsigned t0, unsigned t1) {
    for (;;) {
      unsigned ma = umin4(vf[0], vf[1], vf[2], vf[3]);
      unsigned mb = umin4(vf[4], vf[5], vf[6], vf[7]);
      if (ma >= t0 && mb >= t1) break;
    }
    __threadfence_block();  // acquire
  };

  const int gr = jt * 16 + c, gz = 64 + gr, gn = 128 + gr;

  if (lyr == 0) {
    // ================= LAYER-0 stage =================
    short8 whh0[2][3], wx[3];
#pragma unroll
    for (int g = 0; g < 3; ++g) {
      const int off = ((g * 4 + jt) * 16 + c) * kH + grp * 8;
      whh0[0][g] = cvt8(Whh0 + off);
      whh0[1][g] = cvt8(Whh0 + off + 32);
      short8 f = {0, 0, 0, 0, 0, 0, 0, 0};
      if (grp == 0) {  // W_ih0 is (192 x 3), K zero-padded to 32
        const float* p = Wih0 + ((g * 4 + jt) * 16 + c) * kIN;
        f[0] = (short)f2bf(p[0]); f[1] = (short)f2bf(p[1]); f[2] = (short)f2bf(p[2]);
      }
      wx[g] = f;
    }
    const float b0r  = bih0[gr] + bhh0[gr];
    const float b0z  = bih0[gz] + bhh0[gz];
    const float b0nx = bih0[gn], b0nh = bhh0[gn];

    floatx4 h0D = {0.f, 0.f, 0.f, 0.f};

    auto load_x = [&](int t) -> short8 {
      short8 f = {0, 0, 0, 0, 0, 0, 0, 0};
      if (grp == 0) {
        const float* p = x + ((size_t)(wb + c) * kT + t) * kIN;
        f[0] = (short)f2bf(p[0]); f[1] = (short)f2bf(p[1]); f[2] = (short)f2bf(p[2]);
      }
      return f;
    };
    short8 xf = load_x(0);

#pragma unroll 1
    for (int t = 0; t < kT; ++t) {
      floatx4 ar  = {b0r, b0r, b0r, b0r};
      floatx4 az  = {b0z, b0z, b0z, b0z};
      floatx4 anx = {b0nx, b0nx, b0nx, b0nx};
      floatx4 anh = {b0nh, b0nh, b0nh, b0nh};
      // x-part first: independent of the poll
      ar  = MFMA16(xf, wx[0], ar);
      az  = MFMA16(xf, wx[1], az);
      anx = MFMA16(xf, wx[2], anx);

      // own group wrote h0(t-1); l1 consumed the slot we'll overwrite
      poll((unsigned)t, (t >= W) ? (unsigned)(t - W + 1) : 0u);
      const unsigned short* rs = ring0[(t + W - 1) & (W - 1)];  // h0(t-1); t=0 -> zeros
      short8 hA0 = *(const short8*)(rs + c * LDH + grp * 8);
      short8 hA1 = *(const short8*)(rs + c * LDH + 32 + grp * 8);
      ar  = MFMA16(hA0, whh0[0][0], ar);
      ar  = MFMA16(hA1, whh0[1][0], ar);
      az  = MFMA16(hA0, whh0[0][1], az);
      az  = MFMA16(hA1, whh0[1][1], az);
      anh = MFMA16(hA0, whh0[0][2], anh);
      anh = MFMA16(hA1, whh0[1][2], anh);

      short8 xn = load_x(t + 1 < kT ? t + 1 : t);  // off-path global prefetch

      unsigned short* ws = ring0[t & (W - 1)];
#pragma unroll
      for (int r = 0; r < 4; ++r) {
        float rg = sigm(ar[r]);
        float zg = sigm(az[r]);
        float ng = tanh_(anx[r] + rg * anh[r]);
        float hn = ng + zg * (h0D[r] - ng);
        h0D[r] = hn;
        ws[(grp * 4 + r) * LDH + jt * 16 + c] = f2bf(hn);
      }
      __threadfence_block();        // release: drain ds_writes
      if (lane == 0) vf[jt] = t + 1;
      xf = xn;
    }
  } else {
    // ================= LAYER-1 stage =================
    short8 wih1[2][3], whh1[2][3];
#pragma unroll
    for (int g = 0; g < 3; ++g) {
      const int off = ((g * 4 + jt) * 16 + c) * kH + grp * 8;
      wih1[0][g] = cvt8(Wih1 + off);
      wih1[1][g] = cvt8(Wih1 + off + 32);
      whh1[0][g] = cvt8(Whh1 + off);
      whh1[1][g] = cvt8(Whh1 + off + 32);
    }
    const float b1r  = bih1[gr] + bhh1[gr];
    const float b1z  = bih1[gz] + bhh1[gz];
    const float b1nx = bih1[gn], b1nh = bhh1[gn];

    floatx4 h1D = {0.f, 0.f, 0.f, 0.f};
    const size_t FH = (size_t)kB * kT * kH;
    float* obase = out + ((size_t)(wb + grp * 4) * kT) * kH + jt * 16 + c;

#pragma unroll 1
    for (int t = 0; t < kT; ++t) {
      // h0(t) in ring AND siblings wrote h1(t-1)
      poll((unsigned)(t + 1), (unsigned)t);
      const unsigned short* s0 = ring0[t & (W - 1)];
      const unsigned short* s1 = ring1[(t + 1) & 1];  // h1(t-1); t=0 -> zeros
      short8 h0A0 = *(const short8*)(s0 + c * LDH + grp * 8);
      short8 h0A1 = *(const short8*)(s0 + c * LDH + 32 + grp * 8);
      short8 h1A0 = *(const short8*)(s1 + c * LDH + grp * 8);
      short8 h1A1 = *(const short8*)(s1 + c * LDH + 32 + grp * 8);

      floatx4 ar  = {b1r, b1r, b1r, b1r};
      floatx4 az  = {b1z, b1z, b1z, b1z};
      floatx4 anx = {b1nx, b1nx, b1nx, b1nx};
      floatx4 anh = {b1nh, b1nh, b1nh, b1nh};
      ar  = MFMA16(h1A0, whh1[0][0], ar);
      ar  = MFMA16(h1A1, whh1[1][0], ar);
      az  = MFMA16(h1A0, whh1[0][1], az);
      az  = MFMA16(h1A1, whh1[1][1], az);
      anh = MFMA16(h1A0, whh1[0][2], anh);
      anh = MFMA16(h1A1, whh1[1][2], anh);
      ar  = MFMA16(h0A0, wih1[0][0], ar);
      ar  = MFMA16(h0A1, wih1[1][0], ar);
      az  = MFMA16(h0A0, wih1[0][1], az);
      az  = MFMA16(h0A1, wih1[1][1], az);
      anx = MFMA16(h0A0, wih1[0][2], anx);
      anx = MFMA16(h0A1, wih1[1][2], anx);

      unsigned short* wd = ring1[t & 1];
      float hnv[4];
#pragma unroll
      for (int r = 0; r < 4; ++r) {
        float rg = sigm(ar[r]);
        float zg = sigm(az[r]);
        float ng = tanh_(anx[r] + rg * anh[r]);
        float hn = ng + zg * (h1D[r] - ng);
        h1D[r] = hn;
        wd[(grp * 4 + r) * LDH + jt * 16 + c] = f2bf(hn);
        hnv[r] = hn;
      }
      __threadfence_block();            // release
      if (lane == 0) vf[4 + jt] = t + 1;

      // seq_out straight from registers, after the release (off serial chain)
#pragma unroll
      for (int r = 0; r < 4; ++r)
        obase[(size_t)r * kT * kH + (size_t)t * kH] = hnv[r];
      if (t == kT - 1) {
#pragma unroll
        for (int r = 0; r < 4; ++r)
          out[FH + (size_t)(wb + grp * 4 + r) * kH + jt * 16 + c] = hnv[r];
      }
    }
  }
}

extern "C" void kernel_launch(void* const* d_in, const int* in_sizes, int n_in,
                              void* d_out, int out_size, void* d_ws, size_t ws_size,
                              hipStream_t stream) {
  const float* xp   = (const float*)d_in[0];
  const float* wih0 = (const float*)d_in[1];
  const float* whh0 = (const float*)d_in[2];
  const float* bih0 = (const float*)d_in[3];
  const float* bhh0 = (const float*)d_in[4];
  const float* wih1 = (const float*)d_in[5];
  const float* whh1 = (const float*)d_in[6];
  const float* bih1 = (const float*)d_in[7];
  const float* bhh1 = (const float*)d_in[8];
  float* outp = (float*)d_out;
  hipLaunchKernelGGL(gru_kernel, dim3(32), dim3(512), 0, stream,
                     xp, wih0, whh0, bih0, bhh0, wih1, whh1, bih1, bhh1, outp);
}